// Round 10
// baseline (298.797 us; speedup 1.0000x reference)
//
#include <hip/hip_runtime.h>
#include <hip/hip_bf16.h>
#include <cmath>

// R10 = R9 + crash fix: guard gather addresses when cnt==0 (ev8 slots are
// uninitialized for empty buckets; R9 loaded from garbage srcj before
// masking -> memory fault). srcj forced to 0 (valid row) when cnt==0; the
// existing post-load mask already zeroes the contribution.
//  R9 content: (a) compact ev8[d][rel][8] + rare spill; (b) H1 rel-major +
//  rel-phased csr_agg1 (L2-slice locality); (c) agg2 fused into gemm2c
//  (m2 roundtrip eliminated).

#define IN_DIM 128
#define HID 64
#define OUT_DIM 40
#define NREL 8
#define NCOLS 576   // layer-1 B cols: 8*64 + 64 root
#define K2 576      // layer-2 K: 8*64 rel-means + 64 root
#define CAPR 32     // max per-(dst,rel) bucket (8 fast + 24 spill)
#define SPILLN 24
#define CSTR 16     // cursor stride (ints) = one 64B line per dst (8 used)

typedef __attribute__((ext_vector_type(8))) short short8;
typedef __attribute__((ext_vector_type(4))) short short4v;
typedef __attribute__((ext_vector_type(4))) float floatx4;

static __device__ __forceinline__ short f2bf(float f) {
  __hip_bfloat16 h = __float2bfloat16(f);
  return __builtin_bit_cast(short, h);
}
static __device__ __forceinline__ float bflo(unsigned int u) {
  return __int_as_float(u << 16);
}
static __device__ __forceinline__ float bfhi(unsigned int u) {
  return __int_as_float(u & 0xffff0000u);
}
static __device__ __forceinline__ unsigned int packbf(float x, float y) {
  unsigned int lo = (unsigned short)f2bf(x);
  unsigned int hi = (unsigned short)f2bf(y);
  return lo | (hi << 16);
}
static __device__ __forceinline__ float bf2f(short s) {
  return __int_as_float(((unsigned int)(unsigned short)s) << 16);
}

// ---- pack Bt1, Bt2b, WlB(hi/lo), zero cursor -------------------------------
__global__ void pack_bt(const float* __restrict__ W1, const float* __restrict__ root1,
                        short* __restrict__ Bt1,
                        const float* __restrict__ W2, const float* __restrict__ root2,
                        short* __restrict__ Bt2b,
                        const float* __restrict__ Wl, short* __restrict__ WlB,
                        int* __restrict__ cursor, int nzero4) {
  const int PB1 = (NCOLS * IN_DIM + 255) / 256;   // 288
  const int PB2 = (64 * K2 + 255) / 256;          // 144
  const int PBW = (96 * HID + 255) / 256;         // 24
  int b = blockIdx.x;
  if (b < PB1) {
    int i = b * 256 + threadIdx.x;
    if (i >= NCOLS * IN_DIM) return;
    int c = i / IN_DIM, k = i % IN_DIM;
    float v = (c < NREL * HID)
      ? W1[((size_t)(c >> 6) * IN_DIM + k) * HID + (c & 63)]
      : root1[(size_t)k * HID + (c - NREL * HID)];
    Bt1[i] = f2bf(v);
  } else if (b < PB1 + PB2) {
    int i = (b - PB1) * 256 + threadIdx.x;
    if (i >= 64 * K2) return;
    int col = i / K2, kk = i % K2;
    float v = (kk < NREL * HID)
      ? W2[(size_t)kk * HID + col]
      : root2[(size_t)(kk - NREL * HID) * HID + col];
    Bt2b[i] = f2bf(v);
  } else if (b < PB1 + PB2 + PBW) {
    // WlB[96][64]: rows 0..47 = hi(Wl^T padded), rows 48..95 = lo residual
    int i = (b - PB1 - PB2) * 256 + threadIdx.x;
    if (i >= 96 * HID) return;
    int row = i / HID, k = i % HID;
    int c = row % 48;
    float v = (c < OUT_DIM) ? Wl[(size_t)k * OUT_DIM + c] : 0.f;
    short hi = f2bf(v);
    if (row < 48) WlB[i] = hi;
    else          WlB[i] = f2bf(v - bf2f(hi));
  } else {
    int i = (b - PB1 - PB2 - PBW) * 256 + threadIdx.x;
    if (i < nzero4) {
      int4 z; z.x = 0; z.y = 0; z.z = 0; z.w = 0;
      ((int4*)cursor)[i] = z;
    }
  }
}

// ---- R2-EXACT gemm body; H store is rel-major: H1r[(cy*M + mg)*64 + c] -----
__device__ __forceinline__ void gemm1_body(
    short* As, short* Bs,
    const float* __restrict__ A, const short* __restrict__ Bt,
    const float* __restrict__ bias, short* __restrict__ H,
    unsigned short* __restrict__ AGG, int M, int row0)
{
  constexpr int K = IN_DIM;
  constexpr int AST = K + 8;
  int tid = threadIdx.x;
  int wv = tid >> 6, lane = tid & 63;
  int lm = lane & 15, quad = lane >> 4;

  {
    constexpr int CH = K / 4;
    for (int i = tid; i < 64 * CH; i += 256) {
      int r = i / CH, kq = i % CH;
      int gr = row0 + r; if (gr >= M) gr = M - 1;
      float4 v = *(const float4*)(A + (unsigned)(gr * K + kq * 4));
      short4v s;
      s.x = f2bf(v.x); s.y = f2bf(v.y); s.z = f2bf(v.z); s.w = f2bf(v.w);
      *(short4v*)(As + r * AST + kq * 4) = s;
    }
  }

  const short* ap = As + (16 * wv + lm) * AST + quad * 8;

  for (int cy = 0; cy < 9; ++cy) {
    constexpr int CB = K / 8;
    for (int i = tid; i < 64 * CB; i += 256) {
      int n = i / CB, ko = i % CB;
      short8 v = *(const short8*)(Bt + (unsigned)((cy * 64 + n) * K + ko * 8));
      *(short8*)(Bs + n * AST + ko * 8) = v;
    }
    __syncthreads();

    floatx4 acc[4] = {{0,0,0,0},{0,0,0,0},{0,0,0,0},{0,0,0,0}};
    #pragma unroll
    for (int ks = 0; ks < K / 32; ++ks) {
      short8 a = *(const short8*)(ap + ks * 32);
      #pragma unroll
      for (int nb = 0; nb < 4; ++nb) {
        short8 b = *(const short8*)(Bs + (nb * 16 + lm) * AST + ks * 32 + quad * 8);
        acc[nb] = __builtin_amdgcn_mfma_f32_16x16x32_bf16(a, b, acc[nb], 0, 0, 0);
      }
    }
    __syncthreads();

    int mbase = row0 + 16 * wv + quad * 4;
    if (cy < 8) {
      #pragma unroll
      for (int nb = 0; nb < 4; ++nb) {
        int col = nb * 16 + lm;
        #pragma unroll
        for (int r = 0; r < 4; ++r) {
          int mg = mbase + r;
          if (mg < M)
            H[(((size_t)cy * M + mg) << 6) + col] = f2bf(acc[nb][r]);
        }
      }
    } else {
      #pragma unroll
      for (int nb = 0; nb < 4; ++nb) {
        int col = nb * 16 + lm;
        float bv = bias[col];
        #pragma unroll
        for (int r = 0; r < 4; ++r) {
          int mg = mbase + r;
          if (mg < M)
            AGG[(unsigned)mg * HID + col] = (unsigned short)f2bf(acc[nb][r] + bv);
        }
      }
    }
  }
}

// ---- fused: gemm layer-1 (blocks < GB) + compact (dst,rel) scatter ---------
__global__ __launch_bounds__(256, 4) void gemm1_scatter(
    const float* __restrict__ A, const short* __restrict__ Bt,
    const float* __restrict__ bias, short* __restrict__ H,
    unsigned short* __restrict__ AGG, int M, int GB,
    const int* __restrict__ src, const int* __restrict__ dst,
    const int* __restrict__ et,
    int* __restrict__ cursor, int* __restrict__ ev8,
    int* __restrict__ spill, int E)
{
  constexpr int AST = IN_DIM + 8;
  __shared__ short As[64 * AST];
  __shared__ short Bs[64 * AST];
  if ((int)blockIdx.x < GB) {
    gemm1_body(As, Bs, A, Bt, bias, H, AGG, M, blockIdx.x * 64);
  } else {
    int e = (blockIdx.x - GB) * 256 + threadIdx.x;
    if (e >= E) return;
    int d = dst[e];
    int r = et[e];
    int pos = atomicAdd(&cursor[d * CSTR + r], 1);
    if (pos < 8)
      __builtin_nontemporal_store(src[e], &ev8[(d << 6) + (r << 3) + pos]);
    else if (pos < CAPR)
      __builtin_nontemporal_store(src[e],
          &spill[((d << 3) + r) * SPILLN + pos - 8]);
  }
}

// ---- layer-1 agg: wave per dst, 8 sequential rel phases --------------------
// lane = (slot s, dim-group g). Per phase: 1 masked uint4 load from the rel's
// 6.4MB H1r slice; weighted per-lane partial; ONE 24-shfl tree at the end.
__global__ __launch_bounds__(256) void csr_agg1(
    const short* __restrict__ H1r, const int* __restrict__ cursor,
    const int* __restrict__ ev8, const int* __restrict__ spill,
    unsigned short* __restrict__ h, int N)
{
  int tid = threadIdx.x;
  int wv = tid >> 6, lane = tid & 63;
  int s = lane >> 3, g = lane & 7;
  int d = blockIdx.x * 4 + wv;                  // N divisible by 4

  int evl = ev8[(d << 6) + lane];               // [rel][slot] row, coalesced
  const int* crow = cursor + d * CSTR;
  float pacc[8] = {0.f,0.f,0.f,0.f,0.f,0.f,0.f,0.f};

  #pragma unroll
  for (int r = 0; r < 8; ++r) {
    int cnt = crow[r]; if (cnt > CAPR) cnt = CAPR;
    int cm1 = cnt > 0 ? cnt - 1 : 0;
    int sc = s < cm1 ? s : cm1;
    int sv = __shfl(evl, (r << 3) + sc, 64);
    int srcj = (cnt > 0) ? sv : 0;              // GUARD: empty bucket -> row 0
    uint4 hv = *(const uint4*)((const unsigned short*)H1r
        + (((size_t)r * N + srcj) << 6) + (g << 3));
    if (s >= cnt) { hv.x = 0u; hv.y = 0u; hv.z = 0u; hv.w = 0u; }
    float w = (cnt > 0) ? (1.0f / (float)cnt) : 0.0f;
    pacc[0] += w * bflo(hv.x); pacc[1] += w * bfhi(hv.x);
    pacc[2] += w * bflo(hv.y); pacc[3] += w * bfhi(hv.y);
    pacc[4] += w * bflo(hv.z); pacc[5] += w * bfhi(hv.z);
    pacc[6] += w * bflo(hv.w); pacc[7] += w * bfhi(hv.w);
    if (cnt > 8 && s == 0) {                    // rare tail, counted once
      for (int t = 8; t < cnt; ++t) {
        int sj = spill[((d << 3) + r) * SPILLN + t - 8];
        uint4 h2 = *(const uint4*)((const unsigned short*)H1r
            + (((size_t)r * N + sj) << 6) + (g << 3));
        pacc[0] += w * bflo(h2.x); pacc[1] += w * bfhi(h2.x);
        pacc[2] += w * bflo(h2.y); pacc[3] += w * bfhi(h2.y);
        pacc[4] += w * bflo(h2.z); pacc[5] += w * bfhi(h2.z);
        pacc[6] += w * bflo(h2.w); pacc[7] += w * bfhi(h2.w);
      }
    }
  }
  // deferred tree over the slot axis (lane bits 3..5)
  #pragma unroll
  for (int off = 8; off <= 32; off <<= 1) {
    #pragma unroll
    for (int j = 0; j < 8; ++j) pacc[j] += __shfl_xor(pacc[j], off, 64);
  }
  if (s == 0) {
    unsigned short* hrow = h + ((size_t)d << 6) + (g << 3);
    uint4 sv = *(const uint4*)hrow;             // seed = x@root1 + b1
    float v0 = fmaxf(pacc[0] + bflo(sv.x), 0.f);
    float v1 = fmaxf(pacc[1] + bfhi(sv.x), 0.f);
    float v2 = fmaxf(pacc[2] + bflo(sv.y), 0.f);
    float v3 = fmaxf(pacc[3] + bfhi(sv.y), 0.f);
    float v4 = fmaxf(pacc[4] + bflo(sv.z), 0.f);
    float v5 = fmaxf(pacc[5] + bfhi(sv.z), 0.f);
    float v6 = fmaxf(pacc[6] + bflo(sv.w), 0.f);
    float v7 = fmaxf(pacc[7] + bfhi(sv.w), 0.f);
    uint4 ov;
    ov.x = packbf(v0, v1); ov.y = packbf(v2, v3);
    ov.z = packbf(v4, v5); ov.w = packbf(v6, v7);
    *(uint4*)hrow = ov;
  }
}

// ---- fused agg2 + layer-2 gemm + final linear + log_softmax ----------------
// Phase A: waves build As[64][584] = [mean_r h | h] for 64 dsts by gathering
// h (6.4MB, L2-hot); lane=(rel,g), 16 dsts/wave, 8 batched loads/lane/dst.
// Phase B: R7's gemm2c (swapped MFMA, zb, Wl hi/lo MFMA, in-reg softmax).
__global__ __launch_bounds__(256) void gemm2c(
    const unsigned short* __restrict__ h, const int* __restrict__ cursor,
    const int* __restrict__ ev8, const int* __restrict__ spill,
    const short* __restrict__ Bt2b, const short* __restrict__ WlB,
    const float* __restrict__ b2, const float* __restrict__ bl,
    float* __restrict__ out, int N)
{
  constexpr int AST = 64 + 8;
  constexpr int ASTA = K2 + 8;                  // 584
  __shared__ short As[64 * ASTA];               // 74.75 KB
  __shared__ short Bs[64 * AST];
  __shared__ short zb[64 * AST];
  __shared__ short Wb[96 * AST];
  __shared__ float sb2[64];
  __shared__ float sbl[48];
  int tid = threadIdx.x;
  int wv = tid >> 6, lane = tid & 63;
  int lm = lane & 15, quad = lane >> 4;
  int rel = lane >> 3, g = lane & 7;
  int row0 = blockIdx.x * 64;

  #pragma unroll
  for (int j = 0; j < 3; ++j) {
    int i = tid + j * 256;
    int r = i >> 3, ch = i & 7;
    *(short8*)(Wb + r * AST + ch * 8) = *(const short8*)(WlB + r * 64 + ch * 8);
  }
  if (tid < 64) sb2[tid] = b2[tid];
  if (tid < 48) sbl[tid] = (tid < OUT_DIM) ? bl[tid] : 0.f;

  // ---- phase A: build As rows; wave wv owns dsts wv*16 .. wv*16+15 ----
  for (int it = 0; it < 16; ++it) {
    int dloc = wv * 16 + it;
    int d = row0 + dloc; if (d >= N) d = N - 1;
    int evl = ev8[(d << 6) + lane];
    int cnt = cursor[d * CSTR + rel]; if (cnt > CAPR) cnt = CAPR;
    int cm1 = cnt > 0 ? cnt - 1 : 0;
    float a0 = 0.f, a1 = 0.f, a2 = 0.f, a3 = 0.f;
    float a4 = 0.f, a5 = 0.f, a6 = 0.f, a7 = 0.f;
    #pragma unroll
    for (int ss = 0; ss < 8; ++ss) {
      int sc = ss < cm1 ? ss : cm1;
      int sv = __shfl(evl, (rel << 3) + sc, 64);
      int srcj = (cnt > 0) ? sv : 0;            // GUARD: empty bucket -> row 0
      uint4 hv = *(const uint4*)(h + ((size_t)srcj << 6) + (g << 3));
      if (ss >= cnt) { hv.x = 0u; hv.y = 0u; hv.z = 0u; hv.w = 0u; }
      a0 += bflo(hv.x); a1 += bfhi(hv.x);
      a2 += bflo(hv.y); a3 += bfhi(hv.y);
      a4 += bflo(hv.z); a5 += bfhi(hv.z);
      a6 += bflo(hv.w); a7 += bfhi(hv.w);
    }
    if (cnt > 8) {                              // rare tail
      for (int t = 8; t < cnt; ++t) {
        int sj = spill[((d << 3) + rel) * SPILLN + t - 8];
        uint4 hv = *(const uint4*)(h + ((size_t)sj << 6) + (g << 3));
        a0 += bflo(hv.x); a1 += bfhi(hv.x);
        a2 += bflo(hv.y); a3 += bfhi(hv.y);
        a4 += bflo(hv.z); a5 += bfhi(hv.z);
        a6 += bflo(hv.w); a7 += bfhi(hv.w);
      }
    }
    float w = (cnt > 0) ? (1.0f / (float)cnt) : 0.0f;
    uint4 ov;
    ov.x = packbf(a0 * w, a1 * w); ov.y = packbf(a2 * w, a3 * w);
    ov.z = packbf(a4 * w, a5 * w); ov.w = packbf(a6 * w, a7 * w);
    *(uint4*)(As + dloc * ASTA + (rel << 6) + (g << 3)) = ov;
    if (rel == 0) {                             // root chunk = own h row
      uint4 hv = *(const uint4*)(h + ((size_t)d << 6) + (g << 3));
      *(uint4*)(As + dloc * ASTA + 512 + (g << 3)) = hv;
    }
  }

  // ---- phase B: C[64x64] = As @ Bt2b^T (9 K-chunks), swapped MFMA ----
  floatx4 acc[4] = {{0,0,0,0},{0,0,0,0},{0,0,0,0},{0,0,0,0}};
  for (int kt = 0; kt < 9; ++kt) {
    #pragma unroll
    for (int j = 0; j < 2; ++j) {
      int i = tid + j * 256;
      int r = i >> 3, ch = i & 7;
      *(short8*)(Bs + r * AST + ch * 8) =
          *(const short8*)(Bt2b + (unsigned)(r * K2 + kt * 64 + ch * 8));
    }
    __syncthreads();   // also orders phase-A As writes for first kt
    #pragma unroll
    for (int ks = 0; ks < 2; ++ks) {
      short8 a = *(const short8*)(As + (16 * wv + lm) * ASTA + kt * 64
                                  + ks * 32 + quad * 8);
      #pragma unroll
      for (int nb = 0; nb < 4; ++nb) {
        short8 b = *(const short8*)(Bs + (nb * 16 + lm) * AST + ks * 32 + quad * 8);
        acc[nb] = __builtin_amdgcn_mfma_f32_16x16x32_bf16(b, a, acc[nb], 0, 0, 0);
      }
    }
    __syncthreads();
  }

  int zrow = 16 * wv + lm;
  #pragma unroll
  for (int nb = 0; nb < 4; ++nb) {
    int c0 = nb * 16 + quad * 4;
    float4 bv = *(const float4*)(sb2 + c0);
    short4v s;
    s.x = f2bf(fmaxf(acc[nb][0] + bv.x, 0.f));
    s.y = f2bf(fmaxf(acc[nb][1] + bv.y, 0.f));
    s.z = f2bf(fmaxf(acc[nb][2] + bv.z, 0.f));
    s.w = f2bf(fmaxf(acc[nb][3] + bv.w, 0.f));
    *(short4v*)(zb + zrow * AST + c0) = s;
  }

  floatx4 acc2[3] = {{0,0,0,0},{0,0,0,0},{0,0,0,0}};
  #pragma unroll
  for (int ks = 0; ks < 2; ++ks) {
    short8 a = *(const short8*)(zb + zrow * AST + ks * 32 + quad * 8);
    #pragma unroll
    for (int nb2 = 0; nb2 < 3; ++nb2) {
      short8 bh = *(const short8*)(Wb + (nb2 * 16 + lm) * AST + ks * 32 + quad * 8);
      short8 bl_ = *(const short8*)(Wb + (48 + nb2 * 16 + lm) * AST + ks * 32 + quad * 8);
      acc2[nb2] = __builtin_amdgcn_mfma_f32_16x16x32_bf16(bh, a, acc2[nb2], 0, 0, 0);
      acc2[nb2] = __builtin_amdgcn_mfma_f32_16x16x32_bf16(bl_, a, acc2[nb2], 0, 0, 0);
    }
  }

  float lv[3][4];
  float m = -__builtin_inff();
  #pragma unroll
  for (int nb2 = 0; nb2 < 3; ++nb2) {
    #pragma unroll
    for (int r = 0; r < 4; ++r) {
      int col = nb2 * 16 + quad * 4 + r;
      float t = acc2[nb2][r] + sbl[col];
      lv[nb2][r] = t;
      if (col < OUT_DIM) m = fmaxf(m, t);
    }
  }
  m = fmaxf(m, __shfl_xor(m, 16, 64));
  m = fmaxf(m, __shfl_xor(m, 32, 64));
  float s = 0.f;
  #pragma unroll
  for (int nb2 = 0; nb2 < 3; ++nb2) {
    #pragma unroll
    for (int r = 0; r < 4; ++r) {
      int col = nb2 * 16 + quad * 4 + r;
      if (col < OUT_DIM) s += expf(lv[nb2][r] - m);
    }
  }
  s += __shfl_xor(s, 16, 64);
  s += __shfl_xor(s, 32, 64);
  float lg = logf(s);
  int dd = row0 + zrow;
  if (dd < N) {
    float* orow = out + (size_t)dd * OUT_DIM;
    #pragma unroll
    for (int nb2 = 0; nb2 < 3; ++nb2) {
      #pragma unroll
      for (int r = 0; r < 4; ++r) {
        int col = nb2 * 16 + quad * 4 + r;
        if (col < OUT_DIM) orow[col] = lv[nb2][r] - m - lg;
      }
    }
  }
}

// ---- launch ----------------------------------------------------------------
extern "C" void kernel_launch(void* const* d_in, const int* in_sizes, int n_in,
                              void* d_out, int out_size, void* d_ws, size_t ws_size,
                              hipStream_t stream) {
  const float* x     = (const float*)d_in[0];
  const int*   eidx  = (const int*)d_in[1];
  const int*   etype = (const int*)d_in[2];
  const float* W1    = (const float*)d_in[3];
  const float* root1 = (const float*)d_in[4];
  const float* b1    = (const float*)d_in[5];
  const float* W2    = (const float*)d_in[6];
  const float* root2 = (const float*)d_in[7];
  const float* b2    = (const float*)d_in[8];
  const float* Wl    = (const float*)d_in[9];
  const float* bl    = (const float*)d_in[10];

  int N = in_sizes[0] / IN_DIM;   // 50000
  int E = in_sizes[2];            // 800000
  const int* srcp = eidx;
  const int* dstp = eidx + E;

  char* ws = (char*)d_ws;
  size_t off = 0;
  auto alloc = [&](size_t bytes) -> char* {
    char* p = ws + off;
    off += (bytes + 255) & ~(size_t)255;
    return p;
  };
  short* Bt1    = (short*)alloc((size_t)NCOLS * IN_DIM * 2);
  short* Bt2b   = (short*)alloc((size_t)64 * K2 * 2);
  short* WlB    = (short*)alloc((size_t)96 * HID * 2);
  int*   cursor = (int*)alloc((size_t)N * CSTR * 4);            // 3.2 MB
  int*   ev8    = (int*)alloc((size_t)N * 64 * 4);              // 12.8 MB
  int*   spill  = (int*)alloc((size_t)N * NREL * SPILLN * 4);   // 38.4 MB
  short* H1r    = (short*)alloc((size_t)NREL * N * HID * 2);    // 51.2 MB
  unsigned short* h = (unsigned short*)alloc((size_t)N * HID * 2);  // 6.4 MB

  const int PB1 = (NCOLS * IN_DIM + 255) / 256;   // 288
  const int PB2 = (64 * K2 + 255) / 256;          // 144
  const int PBW = (96 * HID + 255) / 256;         // 24
  int nzero4 = (N * CSTR) / 4;                    // 200000
  int ZB = (nzero4 + 255) / 256;                  // 782
  pack_bt<<<PB1 + PB2 + PBW + ZB, 256, 0, stream>>>(
      W1, root1, Bt1, W2, root2, Bt2b, Wl, WlB, cursor, nzero4);

  int GB = (N + 63) / 64;          // 782 gemm blocks (FIRST)
  int SB = (E + 255) / 256;        // 3125 scatter blocks (trailing)
  gemm1_scatter<<<GB + SB, 256, 0, stream>>>(x, Bt1, b1, H1r, h, N, GB,
                                             srcp, dstp, etype,
                                             cursor, ev8, spill, E);

  csr_agg1<<<N / 4, 256, 0, stream>>>(H1r, cursor, ev8, spill, h, N);

  gemm2c<<<GB, 256, 0, stream>>>(h, cursor, ev8, spill, Bt2b, WlB,
                                 b2, bl, (float*)d_out, N);
}